// Round 6
// baseline (411.207 us; speedup 1.0000x reference)
//
#include <hip/hip_runtime.h>
#include <math.h>

#define F_IN 128
#define HID  32

#define NPB   256      // nodes per bucket (dst >> 8)
#define MAXNB 1024     // max buckets supported by the one-block scan
#define EPB   2048     // edges per block in coarse passes (1172 blocks @ 2.4M)

__device__ __forceinline__ void fma4(float4& a, float s, const float4& w) {
    a.x = fmaf(s, w.x, a.x);
    a.y = fmaf(s, w.y, a.y);
    a.z = fmaf(s, w.z, a.z);
    a.w = fmaf(s, w.w, a.w);
}

// ================= binned CSR build =================

// P1: coarse histogram of dst>>8 via LDS; int4-vectorized edge reads
__global__ __launch_bounds__(256) void k_bhist(const int* __restrict__ dst,
                                               int* __restrict__ bin_hist,
                                               int e, int nbuckets) {
    __shared__ int h[MAXNB];
    int tid = threadIdx.x;
    for (int i = tid; i < nbuckets; i += 256) h[i] = 0;
    __syncthreads();
    int base = blockIdx.x * EPB;
    int end = base + EPB; if (end > e) end = e;
    for (int i = base + tid * 4; i < end; i += 1024) {
        int4 d4 = *(const int4*)&dst[i];
        atomicAdd(&h[d4.x >> 8], 1);
        atomicAdd(&h[d4.y >> 8], 1);
        atomicAdd(&h[d4.z >> 8], 1);
        atomicAdd(&h[d4.w >> 8], 1);
    }
    __syncthreads();
    for (int i = tid; i < nbuckets; i += 256)
        if (h[i]) atomicAdd(&bin_hist[i], h[i]);
}

__global__ __launch_bounds__(1024) void k_bscan(const int* __restrict__ bin_hist,
                                                int* __restrict__ bin_off,
                                                int* __restrict__ bin_cur,
                                                int* __restrict__ offsets,
                                                int nbuckets, int n, int e) {
    __shared__ int sh[MAXNB];
    int t = threadIdx.x;
    int v = (t < nbuckets) ? bin_hist[t] : 0;
    sh[t] = v; __syncthreads();
    for (int off = 1; off < MAXNB; off <<= 1) {
        int a = (t >= off) ? sh[t - off] : 0;
        __syncthreads();
        sh[t] += a;
        __syncthreads();
    }
    int excl = sh[t] - v;
    if (t < nbuckets) { bin_off[t] = excl; bin_cur[t] = excl; }
    if (t == 0) { bin_off[nbuckets] = e; offsets[n] = e; }
}

// P3: partition edges into bucket regions; pack src(18b) | dst_local(8b)<<18
__global__ __launch_bounds__(256) void k_bpart(const int* __restrict__ src,
                                               const int* __restrict__ dst,
                                               int* __restrict__ bin_cur,
                                               unsigned* __restrict__ tmp,
                                               int e, int nbuckets) {
    __shared__ int h[MAXNB];
    __shared__ int lc[MAXNB];
    int tid = threadIdx.x;
    for (int i = tid; i < nbuckets; i += 256) h[i] = 0;
    __syncthreads();
    int base = blockIdx.x * EPB;
    int end = base + EPB; if (end > e) end = e;
    for (int i = base + tid * 4; i < end; i += 1024) {
        int4 d4 = *(const int4*)&dst[i];
        atomicAdd(&h[d4.x >> 8], 1);
        atomicAdd(&h[d4.y >> 8], 1);
        atomicAdd(&h[d4.z >> 8], 1);
        atomicAdd(&h[d4.w >> 8], 1);
    }
    __syncthreads();
    for (int i = tid; i < nbuckets; i += 256) {
        int c = h[i];
        h[i] = c ? atomicAdd(&bin_cur[i], c) : 0;
        lc[i] = 0;
    }
    __syncthreads();
    for (int i = base + tid * 4; i < end; i += 1024) {
        int4 d4 = *(const int4*)&dst[i];
        int4 s4 = *(const int4*)&src[i];
        int b0 = d4.x >> 8, b1 = d4.y >> 8, b2 = d4.z >> 8, b3 = d4.w >> 8;
        int r0 = atomicAdd(&lc[b0], 1);
        int r1 = atomicAdd(&lc[b1], 1);
        int r2 = atomicAdd(&lc[b2], 1);
        int r3 = atomicAdd(&lc[b3], 1);
        tmp[h[b0] + r0] = (unsigned)s4.x | ((unsigned)(d4.x & (NPB - 1)) << 18);
        tmp[h[b1] + r1] = (unsigned)s4.y | ((unsigned)(d4.y & (NPB - 1)) << 18);
        tmp[h[b2] + r2] = (unsigned)s4.z | ((unsigned)(d4.z & (NPB - 1)) << 18);
        tmp[h[b3] + r3] = (unsigned)s4.w | ((unsigned)(d4.w & (NPB - 1)) << 18);
    }
}

__global__ __launch_bounds__(256) void k_bcsr(const unsigned* __restrict__ tmp,
                                              const int* __restrict__ bin_off,
                                              int* __restrict__ es,
                                              int* __restrict__ offsets,
                                              float* __restrict__ dis, int n) {
    __shared__ int cnt[NPB];
    __shared__ int sh[NPB];
    __shared__ int cur[NPB];
    int b = blockIdx.x, t = threadIdx.x;
    cnt[t] = 0;
    __syncthreads();
    int s0 = bin_off[b], s1 = bin_off[b + 1];
    for (int i = s0 + t; i < s1; i += 256)
        atomicAdd(&cnt[(tmp[i] >> 18) & (NPB - 1)], 1);
    __syncthreads();
    int v = cnt[t];
    sh[t] = v; __syncthreads();
    for (int off = 1; off < NPB; off <<= 1) {
        int a = (t >= off) ? sh[t - off] : 0;
        __syncthreads();
        sh[t] += a;
        __syncthreads();
    }
    int excl = sh[t] - v;
    int node = b * NPB + t;
    if (node < n) {
        offsets[node] = s0 + excl;
        dis[node] = rsqrtf((float)(v + 1));
    }
    cur[t] = excl;
    __syncthreads();
    for (int i = s0 + t; i < s1; i += 256) {
        unsigned w = tmp[i];
        int dl = (w >> 18) & (NPB - 1);
        int r = atomicAdd(&cur[dl], 1);
        es[s0 + r] = (int)(w & 0x3FFFFu);
    }
}

// ================= transforms =================

// Staging-free: W in LDS (16 KB); x read directly from global (float4,
// broadcast across the 8 lanes sharing gq). 128 nodes/block.
__global__ __launch_bounds__(256) void k_gemm1(const float* __restrict__ x,
                                               const float* __restrict__ W,
                                               const float* __restrict__ dis,
                                               float* __restrict__ u, int n) {
    __shared__ float Ws[F_IN * HID];
    int tid = threadIdx.x;
    for (int i = tid; i < F_IN * HID; i += 256) Ws[i] = W[i];
    int node0 = blockIdx.x * 128;
    int cg = tid & 7, gq = tid >> 3;
    int row[4];
#pragma unroll
    for (int m = 0; m < 4; ++m) {
        int node = node0 + gq + 32 * m;
        row[m] = (node < n) ? node : 0;
    }
    const float4* x4 = (const float4*)x;
    float4 acc[4];
#pragma unroll
    for (int m = 0; m < 4; ++m) acc[m] = make_float4(0.f, 0.f, 0.f, 0.f);
    __syncthreads();
#pragma unroll 4
    for (int ks = 0; ks < 32; ++ks) {
        float4 xv[4];
#pragma unroll
        for (int m = 0; m < 4; ++m) xv[m] = x4[(size_t)row[m] * 32 + ks];
        float4 w0 = *(const float4*)&Ws[(ks * 4 + 0) * HID + cg * 4];
        float4 w1 = *(const float4*)&Ws[(ks * 4 + 1) * HID + cg * 4];
        float4 w2 = *(const float4*)&Ws[(ks * 4 + 2) * HID + cg * 4];
        float4 w3 = *(const float4*)&Ws[(ks * 4 + 3) * HID + cg * 4];
#pragma unroll
        for (int m = 0; m < 4; ++m) {
            fma4(acc[m], xv[m].x, w0);
            fma4(acc[m], xv[m].y, w1);
            fma4(acc[m], xv[m].z, w2);
            fma4(acc[m], xv[m].w, w3);
        }
    }
#pragma unroll
    for (int m = 0; m < 4; ++m) {
        int node = node0 + gq + 32 * m;
        if (node < n) {
            float ds = dis[node];
            float4 r;
            r.x = acc[m].x * ds; r.y = acc[m].y * ds;
            r.z = acc[m].z * ds; r.w = acc[m].w * ds;
            *(float4*)&u[(size_t)node * HID + cg * 4] = r;
        }
    }
}

__global__ __launch_bounds__(256) void k_gemm2(const float* __restrict__ h,
                                               const float* __restrict__ W,
                                               const float* __restrict__ dis,
                                               float* __restrict__ u, int n) {
    __shared__ float Ws[HID * HID];
    int tid = threadIdx.x;
    for (int i = tid; i < HID * HID; i += 256) Ws[i] = W[i];
    int node0 = blockIdx.x * 128;
    int cg = tid & 7, gq = tid >> 3;
    int row[4];
#pragma unroll
    for (int m = 0; m < 4; ++m) {
        int node = node0 + gq + 32 * m;
        row[m] = (node < n) ? node : 0;
    }
    const float4* h4 = (const float4*)h;
    float4 acc[4];
#pragma unroll
    for (int m = 0; m < 4; ++m) acc[m] = make_float4(0.f, 0.f, 0.f, 0.f);
    __syncthreads();
#pragma unroll
    for (int ks = 0; ks < 8; ++ks) {
        float4 xv[4];
#pragma unroll
        for (int m = 0; m < 4; ++m) xv[m] = h4[(size_t)row[m] * 8 + ks];
        float4 w0 = *(const float4*)&Ws[(ks * 4 + 0) * HID + cg * 4];
        float4 w1 = *(const float4*)&Ws[(ks * 4 + 1) * HID + cg * 4];
        float4 w2 = *(const float4*)&Ws[(ks * 4 + 2) * HID + cg * 4];
        float4 w3 = *(const float4*)&Ws[(ks * 4 + 3) * HID + cg * 4];
#pragma unroll
        for (int m = 0; m < 4; ++m) {
            fma4(acc[m], xv[m].x, w0);
            fma4(acc[m], xv[m].y, w1);
            fma4(acc[m], xv[m].z, w2);
            fma4(acc[m], xv[m].w, w3);
        }
    }
#pragma unroll
    for (int m = 0; m < 4; ++m) {
        int node = node0 + gq + 32 * m;
        if (node < n) {
            float ds = dis[node];
            float4 r;
            r.x = acc[m].x * ds; r.y = acc[m].y * ds;
            r.z = acc[m].z * ds; r.w = acc[m].w * ds;
            *(float4*)&u[(size_t)node * HID + cg * 4] = r;
        }
    }
}

// ================= gather aggregation =================

__global__ __launch_bounds__(256) void k_gather32(const float4* __restrict__ u4,
                                                  const int* __restrict__ es,
                                                  const int* __restrict__ offsets,
                                                  const float* __restrict__ dis,
                                                  const float* __restrict__ b,
                                                  float4* __restrict__ h4, int n) {
    int t = blockIdx.x * 256 + threadIdx.x;
    int node = t >> 3, q = t & 7;
    if (node >= n) return;
    int s0 = offsets[node];
    int s1 = offsets[node + 1];
    float4 acc = u4[(size_t)node * 8 + q];   // self-loop
    int ei = s0;
    for (; ei + 4 <= s1; ei += 4) {
        int e0 = es[ei], e1 = es[ei + 1], e2 = es[ei + 2], e3 = es[ei + 3];
        float4 v0 = u4[(size_t)e0 * 8 + q];
        float4 v1 = u4[(size_t)e1 * 8 + q];
        float4 v2 = u4[(size_t)e2 * 8 + q];
        float4 v3 = u4[(size_t)e3 * 8 + q];
        acc.x += (v0.x + v1.x) + (v2.x + v3.x);
        acc.y += (v0.y + v1.y) + (v2.y + v3.y);
        acc.z += (v0.z + v1.z) + (v2.z + v3.z);
        acc.w += (v0.w + v1.w) + (v2.w + v3.w);
    }
    for (; ei < s1; ++ei) {
        int s = es[ei];
        float4 v = u4[(size_t)s * 8 + q];
        acc.x += v.x; acc.y += v.y; acc.z += v.z; acc.w += v.w;
    }
    float ds = dis[node];
    float4 r;
    r.x = fmaxf(fmaf(ds, acc.x, b[q * 4 + 0]), 0.0f);
    r.y = fmaxf(fmaf(ds, acc.y, b[q * 4 + 1]), 0.0f);
    r.z = fmaxf(fmaf(ds, acc.z, b[q * 4 + 2]), 0.0f);
    r.w = fmaxf(fmaf(ds, acc.w, b[q * 4 + 3]), 0.0f);
    h4[(size_t)node * 8 + q] = r;
}

// Layer-2 gather with fused W3 dot: s[node] = dis * (relu(...)·W3).
__global__ __launch_bounds__(256) void k_gather32_dot(const float4* __restrict__ u4,
                                                      const int* __restrict__ es,
                                                      const int* __restrict__ offsets,
                                                      const float* __restrict__ dis,
                                                      const float* __restrict__ b,
                                                      const float* __restrict__ W3,
                                                      float* __restrict__ s, int n) {
    int t = blockIdx.x * 256 + threadIdx.x;
    int node = t >> 3, q = t & 7;
    if (node >= n) return;
    int s0 = offsets[node];
    int s1 = offsets[node + 1];
    float4 acc = u4[(size_t)node * 8 + q];
    int ei = s0;
    for (; ei + 4 <= s1; ei += 4) {
        int e0 = es[ei], e1 = es[ei + 1], e2 = es[ei + 2], e3 = es[ei + 3];
        float4 v0 = u4[(size_t)e0 * 8 + q];
        float4 v1 = u4[(size_t)e1 * 8 + q];
        float4 v2 = u4[(size_t)e2 * 8 + q];
        float4 v3 = u4[(size_t)e3 * 8 + q];
        acc.x += (v0.x + v1.x) + (v2.x + v3.x);
        acc.y += (v0.y + v1.y) + (v2.y + v3.y);
        acc.z += (v0.z + v1.z) + (v2.z + v3.z);
        acc.w += (v0.w + v1.w) + (v2.w + v3.w);
    }
    for (; ei < s1; ++ei) {
        int sc = es[ei];
        float4 v = u4[(size_t)sc * 8 + q];
        acc.x += v.x; acc.y += v.y; acc.z += v.z; acc.w += v.w;
    }
    float ds = dis[node];
    float4 r;
    r.x = fmaxf(fmaf(ds, acc.x, b[q * 4 + 0]), 0.0f);
    r.y = fmaxf(fmaf(ds, acc.y, b[q * 4 + 1]), 0.0f);
    r.z = fmaxf(fmaf(ds, acc.z, b[q * 4 + 2]), 0.0f);
    r.w = fmaxf(fmaf(ds, acc.w, b[q * 4 + 3]), 0.0f);
    float p = r.x * W3[q * 4 + 0] + r.y * W3[q * 4 + 1]
            + r.z * W3[q * 4 + 2] + r.w * W3[q * 4 + 3];
    p += __shfl_down(p, 4, 8);
    p += __shfl_down(p, 2, 8);
    p += __shfl_down(p, 1, 8);
    if (q == 0) s[node] = p * ds;
}

__global__ void k_gather1(const float* __restrict__ sv, const int* __restrict__ es,
                          const int* __restrict__ offsets, const float* __restrict__ dis,
                          const float* __restrict__ b3, float* __restrict__ out, int n) {
    int d = blockIdx.x * 256 + threadIdx.x;
    if (d >= n) return;
    float acc = sv[d];
    int s0 = offsets[d], s1 = offsets[d + 1];
    int ei = s0;
    for (; ei + 4 <= s1; ei += 4) {
        float v0 = sv[es[ei]], v1 = sv[es[ei + 1]];
        float v2 = sv[es[ei + 2]], v3 = sv[es[ei + 3]];
        acc += (v0 + v1) + (v2 + v3);
    }
    for (; ei < s1; ++ei) acc += sv[es[ei]];
    float z = dis[d] * acc + b3[0];
    out[d] = 1.0f / (1.0f + expf(-z));
}

// ================= launch =================

extern "C" void kernel_launch(void* const* d_in, const int* in_sizes, int n_in,
                              void* d_out, int out_size, void* d_ws, size_t ws_size,
                              hipStream_t stream) {
    const float* x  = (const float*)d_in[0];
    const int*   ei = (const int*)d_in[1];
    const float* W1 = (const float*)d_in[2];
    const float* b1 = (const float*)d_in[3];
    const float* W2 = (const float*)d_in[4];
    const float* b2 = (const float*)d_in[5];
    const float* W3 = (const float*)d_in[6];
    const float* b3 = (const float*)d_in[7];
    float* out = (float*)d_out;

    int n = out_size;             // 150000
    int e = in_sizes[1] / 2;      // 2400000
    const int* src = ei;
    const int* dst = ei + e;

    int nbuckets = (n + NPB - 1) / NPB;   // 586

    float* A        = (float*)d_ws;                 // n*32 f
    float* B        = A + (size_t)n * HID;          // n*32 f (aliases tmp during CSR build)
    float* dis      = B + (size_t)n * HID;          // n f
    float* Cs       = dis + n;                      // n f
    int*   offsets  = (int*)(Cs + n);               // n+1 i
    int*   es       = offsets + (n + 1);            // e i
    int*   bin_hist = es + e;                       // nbuckets i
    int*   bin_off  = bin_hist + nbuckets;          // nbuckets+1 i
    int*   bin_cur  = bin_off + (nbuckets + 1);     // nbuckets i
    unsigned* tmp   = (unsigned*)B;

    dim3 blk(256);
    int gN    = (n + 255) / 256;
    int gN8   = (n * 8 + 255) / 256;
    int g128  = (n + 127) / 128;
    int gEb   = (e + EPB - 1) / EPB;   // 1172

    // ---- CSR build ----
    hipMemsetAsync(bin_hist, 0, (size_t)nbuckets * sizeof(int), stream);
    k_bhist<<<gEb, blk, 0, stream>>>(dst, bin_hist, e, nbuckets);
    k_bscan<<<1, 1024, 0, stream>>>(bin_hist, bin_off, bin_cur, offsets, nbuckets, n, e);
    k_bpart<<<gEb, blk, 0, stream>>>(src, dst, bin_cur, tmp, e, nbuckets);
    k_bcsr <<<nbuckets, blk, 0, stream>>>(tmp, bin_off, es, offsets, dis, n);

    // ---- layer 1 ----
    k_gemm1   <<<g128, blk, 0, stream>>>(x, W1, dis, A, n);
    k_gather32<<<gN8,  blk, 0, stream>>>((const float4*)A, es, offsets, dis, b1, (float4*)B, n);

    // ---- layer 2 (+ fused layer-3 transform) ----
    k_gemm2       <<<g128, blk, 0, stream>>>(B, W2, dis, A, n);
    k_gather32_dot<<<gN8,  blk, 0, stream>>>((const float4*)A, es, offsets, dis, b2, W3, Cs, n);

    // ---- layer 3 aggregation ----
    k_gather1<<<gN, blk, 0, stream>>>(Cs, es, offsets, dis, b3, out, n);
}

// Round 7
// 359.343 us; speedup vs baseline: 1.1443x; 1.1443x over previous
//
#include <hip/hip_runtime.h>
#include <math.h>

#define F_IN 128
#define HID  32

#define NPB   256      // nodes per bucket (dst >> 8)
#define MAXNB 1024     // max buckets supported by the one-block scan
#define EPB   8192     // edges per block in coarse passes (293 blocks @ 2.4M)
#define BLK_E 1024     // threads per block for coarse passes (16 waves/CU)

__device__ __forceinline__ void fma4(float4& a, float s, const float4& w) {
    a.x = fmaf(s, w.x, a.x);
    a.y = fmaf(s, w.y, a.y);
    a.z = fmaf(s, w.z, a.z);
    a.w = fmaf(s, w.w, a.w);
}

// ================= binned CSR build =================

// P1: coarse histogram of dst>>8 via LDS. 1024 threads, 8 edges/thread.
__global__ __launch_bounds__(BLK_E) void k_bhist(const int* __restrict__ dst,
                                                 int* __restrict__ bin_hist,
                                                 int e, int nbuckets) {
    __shared__ int h[MAXNB];
    int tid = threadIdx.x;
    for (int i = tid; i < nbuckets; i += BLK_E) h[i] = 0;
    __syncthreads();
    int base = blockIdx.x * EPB;
    int end = base + EPB; if (end > e) end = e;
    for (int i = base + tid; i < end; i += BLK_E)
        atomicAdd(&h[dst[i] >> 8], 1);
    __syncthreads();
    for (int i = tid; i < nbuckets; i += BLK_E)
        if (h[i]) atomicAdd(&bin_hist[i], h[i]);
}

__global__ __launch_bounds__(1024) void k_bscan(const int* __restrict__ bin_hist,
                                                int* __restrict__ bin_off,
                                                int* __restrict__ bin_cur,
                                                int* __restrict__ offsets,
                                                int nbuckets, int n, int e) {
    __shared__ int sh[MAXNB];
    int t = threadIdx.x;
    int v = (t < nbuckets) ? bin_hist[t] : 0;
    sh[t] = v; __syncthreads();
    for (int off = 1; off < MAXNB; off <<= 1) {
        int a = (t >= off) ? sh[t - off] : 0;
        __syncthreads();
        sh[t] += a;
        __syncthreads();
    }
    int excl = sh[t] - v;
    if (t < nbuckets) { bin_off[t] = excl; bin_cur[t] = excl; }
    if (t == 0) { bin_off[nbuckets] = e; offsets[n] = e; }
}

// P3: partition edges into bucket regions; pack src(18b) | dst_local(8b)<<18.
// 1024 threads, scalar loop: long per-bucket runs + independent atomics.
__global__ __launch_bounds__(BLK_E) void k_bpart(const int* __restrict__ src,
                                                 const int* __restrict__ dst,
                                                 int* __restrict__ bin_cur,
                                                 unsigned* __restrict__ tmp,
                                                 int e, int nbuckets) {
    __shared__ int h[MAXNB];
    __shared__ int lc[MAXNB];
    int tid = threadIdx.x;
    for (int i = tid; i < nbuckets; i += BLK_E) h[i] = 0;
    __syncthreads();
    int base = blockIdx.x * EPB;
    int end = base + EPB; if (end > e) end = e;
    for (int i = base + tid; i < end; i += BLK_E)
        atomicAdd(&h[dst[i] >> 8], 1);
    __syncthreads();
    for (int i = tid; i < nbuckets; i += BLK_E) {
        int c = h[i];
        h[i] = c ? atomicAdd(&bin_cur[i], c) : 0;
        lc[i] = 0;
    }
    __syncthreads();
    for (int i = base + tid; i < end; i += BLK_E) {
        int d = dst[i];
        int b = d >> 8;
        int r = atomicAdd(&lc[b], 1);
        tmp[h[b] + r] = (unsigned)src[i] | ((unsigned)(d & (NPB - 1)) << 18);
    }
}

__global__ __launch_bounds__(256) void k_bcsr(const unsigned* __restrict__ tmp,
                                              const int* __restrict__ bin_off,
                                              int* __restrict__ es,
                                              int* __restrict__ offsets,
                                              float* __restrict__ dis, int n) {
    __shared__ int cnt[NPB];
    __shared__ int sh[NPB];
    __shared__ int cur[NPB];
    int b = blockIdx.x, t = threadIdx.x;
    cnt[t] = 0;
    __syncthreads();
    int s0 = bin_off[b], s1 = bin_off[b + 1];
    for (int i = s0 + t; i < s1; i += 256)
        atomicAdd(&cnt[(tmp[i] >> 18) & (NPB - 1)], 1);
    __syncthreads();
    int v = cnt[t];
    sh[t] = v; __syncthreads();
    for (int off = 1; off < NPB; off <<= 1) {
        int a = (t >= off) ? sh[t - off] : 0;
        __syncthreads();
        sh[t] += a;
        __syncthreads();
    }
    int excl = sh[t] - v;
    int node = b * NPB + t;
    if (node < n) {
        offsets[node] = s0 + excl;
        dis[node] = rsqrtf((float)(v + 1));
    }
    cur[t] = excl;
    __syncthreads();
    for (int i = s0 + t; i < s1; i += 256) {
        unsigned w = tmp[i];
        int dl = (w >> 18) & (NPB - 1);
        int r = atomicAdd(&cur[dl], 1);
        es[s0 + r] = (int)(w & 0x3FFFFu);
    }
}

// ================= transforms =================

// Staging-free: W in LDS (16 KB); x read directly from global (float4,
// broadcast across the 8 lanes sharing gq). 128 nodes/block.
__global__ __launch_bounds__(256) void k_gemm1(const float* __restrict__ x,
                                               const float* __restrict__ W,
                                               const float* __restrict__ dis,
                                               float* __restrict__ u, int n) {
    __shared__ float Ws[F_IN * HID];
    int tid = threadIdx.x;
    for (int i = tid; i < F_IN * HID; i += 256) Ws[i] = W[i];
    int node0 = blockIdx.x * 128;
    int cg = tid & 7, gq = tid >> 3;
    int row[4];
#pragma unroll
    for (int m = 0; m < 4; ++m) {
        int node = node0 + gq + 32 * m;
        row[m] = (node < n) ? node : 0;
    }
    const float4* x4 = (const float4*)x;
    float4 acc[4];
#pragma unroll
    for (int m = 0; m < 4; ++m) acc[m] = make_float4(0.f, 0.f, 0.f, 0.f);
    __syncthreads();
#pragma unroll 4
    for (int ks = 0; ks < 32; ++ks) {
        float4 xv[4];
#pragma unroll
        for (int m = 0; m < 4; ++m) xv[m] = x4[(size_t)row[m] * 32 + ks];
        float4 w0 = *(const float4*)&Ws[(ks * 4 + 0) * HID + cg * 4];
        float4 w1 = *(const float4*)&Ws[(ks * 4 + 1) * HID + cg * 4];
        float4 w2 = *(const float4*)&Ws[(ks * 4 + 2) * HID + cg * 4];
        float4 w3 = *(const float4*)&Ws[(ks * 4 + 3) * HID + cg * 4];
#pragma unroll
        for (int m = 0; m < 4; ++m) {
            fma4(acc[m], xv[m].x, w0);
            fma4(acc[m], xv[m].y, w1);
            fma4(acc[m], xv[m].z, w2);
            fma4(acc[m], xv[m].w, w3);
        }
    }
#pragma unroll
    for (int m = 0; m < 4; ++m) {
        int node = node0 + gq + 32 * m;
        if (node < n) {
            float ds = dis[node];
            float4 r;
            r.x = acc[m].x * ds; r.y = acc[m].y * ds;
            r.z = acc[m].z * ds; r.w = acc[m].w * ds;
            *(float4*)&u[(size_t)node * HID + cg * 4] = r;
        }
    }
}

__global__ __launch_bounds__(256) void k_gemm2(const float* __restrict__ h,
                                               const float* __restrict__ W,
                                               const float* __restrict__ dis,
                                               float* __restrict__ u, int n) {
    __shared__ float Ws[HID * HID];
    int tid = threadIdx.x;
    for (int i = tid; i < HID * HID; i += 256) Ws[i] = W[i];
    int node0 = blockIdx.x * 128;
    int cg = tid & 7, gq = tid >> 3;
    int row[4];
#pragma unroll
    for (int m = 0; m < 4; ++m) {
        int node = node0 + gq + 32 * m;
        row[m] = (node < n) ? node : 0;
    }
    const float4* h4 = (const float4*)h;
    float4 acc[4];
#pragma unroll
    for (int m = 0; m < 4; ++m) acc[m] = make_float4(0.f, 0.f, 0.f, 0.f);
    __syncthreads();
#pragma unroll
    for (int ks = 0; ks < 8; ++ks) {
        float4 xv[4];
#pragma unroll
        for (int m = 0; m < 4; ++m) xv[m] = h4[(size_t)row[m] * 8 + ks];
        float4 w0 = *(const float4*)&Ws[(ks * 4 + 0) * HID + cg * 4];
        float4 w1 = *(const float4*)&Ws[(ks * 4 + 1) * HID + cg * 4];
        float4 w2 = *(const float4*)&Ws[(ks * 4 + 2) * HID + cg * 4];
        float4 w3 = *(const float4*)&Ws[(ks * 4 + 3) * HID + cg * 4];
#pragma unroll
        for (int m = 0; m < 4; ++m) {
            fma4(acc[m], xv[m].x, w0);
            fma4(acc[m], xv[m].y, w1);
            fma4(acc[m], xv[m].z, w2);
            fma4(acc[m], xv[m].w, w3);
        }
    }
#pragma unroll
    for (int m = 0; m < 4; ++m) {
        int node = node0 + gq + 32 * m;
        if (node < n) {
            float ds = dis[node];
            float4 r;
            r.x = acc[m].x * ds; r.y = acc[m].y * ds;
            r.z = acc[m].z * ds; r.w = acc[m].w * ds;
            *(float4*)&u[(size_t)node * HID + cg * 4] = r;
        }
    }
}

// ================= gather aggregation =================

__global__ __launch_bounds__(256) void k_gather32(const float4* __restrict__ u4,
                                                  const int* __restrict__ es,
                                                  const int* __restrict__ offsets,
                                                  const float* __restrict__ dis,
                                                  const float* __restrict__ b,
                                                  float4* __restrict__ h4, int n) {
    int t = blockIdx.x * 256 + threadIdx.x;
    int node = t >> 3, q = t & 7;
    if (node >= n) return;
    int s0 = offsets[node];
    int s1 = offsets[node + 1];
    float4 acc = u4[(size_t)node * 8 + q];   // self-loop
    int ei = s0;
    for (; ei + 4 <= s1; ei += 4) {
        int e0 = es[ei], e1 = es[ei + 1], e2 = es[ei + 2], e3 = es[ei + 3];
        float4 v0 = u4[(size_t)e0 * 8 + q];
        float4 v1 = u4[(size_t)e1 * 8 + q];
        float4 v2 = u4[(size_t)e2 * 8 + q];
        float4 v3 = u4[(size_t)e3 * 8 + q];
        acc.x += (v0.x + v1.x) + (v2.x + v3.x);
        acc.y += (v0.y + v1.y) + (v2.y + v3.y);
        acc.z += (v0.z + v1.z) + (v2.z + v3.z);
        acc.w += (v0.w + v1.w) + (v2.w + v3.w);
    }
    for (; ei < s1; ++ei) {
        int s = es[ei];
        float4 v = u4[(size_t)s * 8 + q];
        acc.x += v.x; acc.y += v.y; acc.z += v.z; acc.w += v.w;
    }
    float ds = dis[node];
    float4 r;
    r.x = fmaxf(fmaf(ds, acc.x, b[q * 4 + 0]), 0.0f);
    r.y = fmaxf(fmaf(ds, acc.y, b[q * 4 + 1]), 0.0f);
    r.z = fmaxf(fmaf(ds, acc.z, b[q * 4 + 2]), 0.0f);
    r.w = fmaxf(fmaf(ds, acc.w, b[q * 4 + 3]), 0.0f);
    h4[(size_t)node * 8 + q] = r;
}

// Layer-2 gather with fused W3 dot: s[node] = dis * (relu(...)·W3).
__global__ __launch_bounds__(256) void k_gather32_dot(const float4* __restrict__ u4,
                                                      const int* __restrict__ es,
                                                      const int* __restrict__ offsets,
                                                      const float* __restrict__ dis,
                                                      const float* __restrict__ b,
                                                      const float* __restrict__ W3,
                                                      float* __restrict__ s, int n) {
    int t = blockIdx.x * 256 + threadIdx.x;
    int node = t >> 3, q = t & 7;
    if (node >= n) return;
    int s0 = offsets[node];
    int s1 = offsets[node + 1];
    float4 acc = u4[(size_t)node * 8 + q];
    int ei = s0;
    for (; ei + 4 <= s1; ei += 4) {
        int e0 = es[ei], e1 = es[ei + 1], e2 = es[ei + 2], e3 = es[ei + 3];
        float4 v0 = u4[(size_t)e0 * 8 + q];
        float4 v1 = u4[(size_t)e1 * 8 + q];
        float4 v2 = u4[(size_t)e2 * 8 + q];
        float4 v3 = u4[(size_t)e3 * 8 + q];
        acc.x += (v0.x + v1.x) + (v2.x + v3.x);
        acc.y += (v0.y + v1.y) + (v2.y + v3.y);
        acc.z += (v0.z + v1.z) + (v2.z + v3.z);
        acc.w += (v0.w + v1.w) + (v2.w + v3.w);
    }
    for (; ei < s1; ++ei) {
        int sc = es[ei];
        float4 v = u4[(size_t)sc * 8 + q];
        acc.x += v.x; acc.y += v.y; acc.z += v.z; acc.w += v.w;
    }
    float ds = dis[node];
    float4 r;
    r.x = fmaxf(fmaf(ds, acc.x, b[q * 4 + 0]), 0.0f);
    r.y = fmaxf(fmaf(ds, acc.y, b[q * 4 + 1]), 0.0f);
    r.z = fmaxf(fmaf(ds, acc.z, b[q * 4 + 2]), 0.0f);
    r.w = fmaxf(fmaf(ds, acc.w, b[q * 4 + 3]), 0.0f);
    float p = r.x * W3[q * 4 + 0] + r.y * W3[q * 4 + 1]
            + r.z * W3[q * 4 + 2] + r.w * W3[q * 4 + 3];
    p += __shfl_down(p, 4, 8);
    p += __shfl_down(p, 2, 8);
    p += __shfl_down(p, 1, 8);
    if (q == 0) s[node] = p * ds;
}

__global__ void k_gather1(const float* __restrict__ sv, const int* __restrict__ es,
                          const int* __restrict__ offsets, const float* __restrict__ dis,
                          const float* __restrict__ b3, float* __restrict__ out, int n) {
    int d = blockIdx.x * 256 + threadIdx.x;
    if (d >= n) return;
    float acc = sv[d];
    int s0 = offsets[d], s1 = offsets[d + 1];
    int ei = s0;
    for (; ei + 4 <= s1; ei += 4) {
        float v0 = sv[es[ei]], v1 = sv[es[ei + 1]];
        float v2 = sv[es[ei + 2]], v3 = sv[es[ei + 3]];
        acc += (v0 + v1) + (v2 + v3);
    }
    for (; ei < s1; ++ei) acc += sv[es[ei]];
    float z = dis[d] * acc + b3[0];
    out[d] = 1.0f / (1.0f + expf(-z));
}

// ================= launch =================

extern "C" void kernel_launch(void* const* d_in, const int* in_sizes, int n_in,
                              void* d_out, int out_size, void* d_ws, size_t ws_size,
                              hipStream_t stream) {
    const float* x  = (const float*)d_in[0];
    const int*   ei = (const int*)d_in[1];
    const float* W1 = (const float*)d_in[2];
    const float* b1 = (const float*)d_in[3];
    const float* W2 = (const float*)d_in[4];
    const float* b2 = (const float*)d_in[5];
    const float* W3 = (const float*)d_in[6];
    const float* b3 = (const float*)d_in[7];
    float* out = (float*)d_out;

    int n = out_size;             // 150000
    int e = in_sizes[1] / 2;      // 2400000
    const int* src = ei;
    const int* dst = ei + e;

    int nbuckets = (n + NPB - 1) / NPB;   // 586

    float* A        = (float*)d_ws;                 // n*32 f
    float* B        = A + (size_t)n * HID;          // n*32 f (aliases tmp during CSR build)
    float* dis      = B + (size_t)n * HID;          // n f
    float* Cs       = dis + n;                      // n f
    int*   offsets  = (int*)(Cs + n);               // n+1 i
    int*   es       = offsets + (n + 1);            // e i
    int*   bin_hist = es + e;                       // nbuckets i
    int*   bin_off  = bin_hist + nbuckets;          // nbuckets+1 i
    int*   bin_cur  = bin_off + (nbuckets + 1);     // nbuckets i
    unsigned* tmp   = (unsigned*)B;

    dim3 blk(256);
    int gN    = (n + 255) / 256;
    int gN8   = (n * 8 + 255) / 256;
    int g128  = (n + 127) / 128;
    int gEb   = (e + EPB - 1) / EPB;   // 293

    // ---- CSR build ----
    hipMemsetAsync(bin_hist, 0, (size_t)nbuckets * sizeof(int), stream);
    k_bhist<<<gEb, dim3(BLK_E), 0, stream>>>(dst, bin_hist, e, nbuckets);
    k_bscan<<<1, 1024, 0, stream>>>(bin_hist, bin_off, bin_cur, offsets, nbuckets, n, e);
    k_bpart<<<gEb, dim3(BLK_E), 0, stream>>>(src, dst, bin_cur, tmp, e, nbuckets);
    k_bcsr <<<nbuckets, blk, 0, stream>>>(tmp, bin_off, es, offsets, dis, n);

    // ---- layer 1 ----
    k_gemm1   <<<g128, blk, 0, stream>>>(x, W1, dis, A, n);
    k_gather32<<<gN8,  blk, 0, stream>>>((const float4*)A, es, offsets, dis, b1, (float4*)B, n);

    // ---- layer 2 (+ fused layer-3 transform) ----
    k_gemm2       <<<g128, blk, 0, stream>>>(B, W2, dis, A, n);
    k_gather32_dot<<<gN8,  blk, 0, stream>>>((const float4*)A, es, offsets, dis, b2, W3, Cs, n);

    // ---- layer 3 aggregation ----
    k_gather1<<<gN, blk, 0, stream>>>(Cs, es, offsets, dis, b3, out, n);
}